// Round 6
// baseline (131.705 us; speedup 1.0000x reference)
//
#include <hip/hip_runtime.h>
#include <math.h>

#define B_ 2
#define C_ 128
#define H_ 64
#define W_ 64
#define F_ 16
#define U_ 9
#define MD_ 4
#define UV_ 81
#define HW_ (H_*W_)
#define BF_ (B_*F_)

typedef float f32x4 __attribute__((ext_vector_type(4)));
typedef float f32x2 __attribute__((ext_vector_type(2)));
typedef _Float16 f16x2 __attribute__((ext_vector_type(2)));
typedef _Float16 f16x4 __attribute__((ext_vector_type(4)));
typedef _Float16 f16x8 __attribute__((ext_vector_type(8)));

// Scales (exact powers of two; leaky_relu commutes with positive scaling).
// fp16 hi/lo split -> ~2^-21 rel error per term (verified passing r2/r4/r5).
#define XSCALE   64.0f
#define WSCALE   256.0f
#define UNSCALE  (1.0f / 16384.0f)

// LDS map (floats), per 512-thr block (16-px tile):
//  [0, 7776)      tarT[(r*24+col)*36 + c]   r=0..8, col=0..23, c=0..31 (per kc)
//  [7776, 9888)   refT[px*132 + c]          px=0..15, c=0..127 (all kc, staged once)
//  epilogue reuse [0, 5832): pvol[(fl*81+uv)*18 + px]
//  [9888,10400)   sm ; [10400,10912) si ; [10912,13984) sred[6][512]
#define TARB 0
#define REFO 7776
#define SM_  9888
#define SI_  10400
#define SU_  10912
#define LDSZ 13984

static __device__ __forceinline__ f16x8 cat4(f16x2 a, f16x2 b, f16x2 c, f16x2 d) {
    f16x4 ab = __builtin_shufflevector(a, b, 0, 1, 2, 3);
    f16x4 cd = __builtin_shufflevector(c, d, 0, 1, 2, 3);
    return __builtin_shufflevector(ab, cd, 0, 1, 2, 3, 4, 5, 6, 7);
}

// exact hi/lo fp16 split of a packed f32 pair
static __device__ __forceinline__ void split2(f32x2 p, f16x2& hi, f16x2& lo) {
    hi = __builtin_bit_cast(f16x2, __builtin_amdgcn_cvt_pkrtz(p.x, p.y));
    f32x2 hf; hf.x = (float)hi.x; hf.y = (float)hi.y;
    f32x2 l = p - hf;
    lo = __builtin_bit_cast(f16x2, __builtin_amdgcn_cvt_pkrtz(l.x, l.y));
}

// Fused cost-volume + flow_reg v2.
// Block = 512 thr = 8 waves = 8 uv-chunks (11,10,10,...,10 ascending), 16-px tile.
// Grid = 512 = (b, y, xq) XCD-chunked -> 2 blocks/CU, 16 waves/CU (4/SIMD).
// MFMA 16x16x32_f16: A = W[16f][32c], B = X[32c][16px]; D row f=grp*4+r, col px=ml
// (fragment mapping verified by passing r2/r4/r5 runs).
__global__ __launch_bounds__(512, 4)
void fused_kernel(const float* __restrict__ ref,
                  const float* __restrict__ tar,
                  const float* __restrict__ pw,
                  float* __restrict__ out0) {
    const int t    = threadIdx.x;
    const int lane = t & 63;
    const int wid  = t >> 6;            // wave = uv-chunk
    const int ml   = lane & 15;         // B col = pixel ; A row = f
    const int grp  = lane >> 4;         // k-group (c = grp*8+j) ; D: f = grp*4+r

    // XCD-chunked bijective decode: grid 512 = 8 XCD x 64 contiguous (b,y,xq)
    const int n0 = blockIdx.x;
    const int L  = (n0 & 7) * 64 + (n0 >> 3);
    const int b  = L >> 8;
    const int y  = (L >> 2) & 63;
    const int xq = L & 3;
    const int x0 = xq * 16;

    const int start = wid ? (1 + wid * 10) : 0;   // chunk [start, start+n)
    // n = wid ? 10 : 11

    __shared__ float lds[LDSZ];

    const float* refB = ref + ((size_t)b * C_) * HW_ + y * W_ + x0;
    const float* tarB = tar + ((size_t)b * C_) * HW_;

    // uv decode for this wave's chunk (static-indexed; i=10 only used by wave 0)
    int uA[11], vA[11];
    #pragma unroll
    for (int i = 0; i < 11; ++i) {
        int uv = start + i;
        int uu = uv / 9;
        uA[i] = uu; vA[i] = uv - uu * 9;
    }

    // ---- stage refT once (all 128 c), scaled x64 ----
    #pragma unroll
    for (int it = 0; it < 4; ++it) {
        int idx = it * 512 + t;
        int c = idx >> 4, px = idx & 15;
        lds[REFO + px * 132 + c] = refB[(size_t)c * HW_ + px] * XSCALE;
    }

    float nstg[14];
    // tar tile per kc: 32c x 9r x 24col = 6912 elements, OOB -> 0
#define SISSUE(KC) {                                                          \
    _Pragma("unroll")                                                         \
    for (int it = 0; it < 14; ++it) {                                         \
        int idx = it * 512 + t;                                               \
        int c0  = idx / 216;                                                  \
        int rem = idx - c0 * 216;                                             \
        int r   = rem / 24;                                                   \
        int col = rem - r * 24;                                               \
        int ysr = y + r - 4;                                                  \
        int xg  = x0 - 4 + col;                                               \
        bool ok = (idx < 6912) && ((unsigned)ysr < 64u) && ((unsigned)xg < 64u); \
        int cc  = c0 > 31 ? 31 : c0;                                          \
        int ysc = ysr < 0 ? 0 : (ysr > 63 ? 63 : ysr);                        \
        int xgc = xg  < 0 ? 0 : (xg  > 63 ? 63 : xg);                         \
        float vL = tarB[(size_t)((KC) * 32 + cc) * HW_ + ysc * W_ + xgc];     \
        nstg[it] = ok ? vL : 0.f;                                             \
    } }

#define SWRITE() {                                                            \
    _Pragma("unroll")                                                         \
    for (int it = 0; it < 14; ++it) {                                         \
        int idx = it * 512 + t;                                               \
        if (idx < 6912) {                                                     \
            int c0  = idx / 216;                                              \
            int rem = idx - c0 * 216;                                         \
            lds[rem * 36 + c0] = nstg[it];                                    \
        }                                                                     \
    } }

    f32x4 acc[11];
    #pragma unroll
    for (int i = 0; i < 11; ++i) acc[i] = f32x4{0.f, 0.f, 0.f, 0.f};

    SISSUE(0);

    for (int kc = 0; kc < 4; ++kc) {
        f32x4 wa = *(const f32x4*)(pw + ml * C_ + kc * 32 + grp * 8);
        f32x4 wb = *(const f32x4*)(pw + ml * C_ + kc * 32 + grp * 8 + 4);

        __syncthreads();                 // previous chunk's readers done
        SWRITE();
        if (kc < 3) SISSUE(kc + 1);      // next chunk in flight during compute
        __syncthreads();                 // staged tile ready

        f16x2 wh[4], wl[4];
        {
            f32x2 p;
            p.x = wa.x * WSCALE; p.y = wa.y * WSCALE; split2(p, wh[0], wl[0]);
            p.x = wa.z * WSCALE; p.y = wa.w * WSCALE; split2(p, wh[1], wl[1]);
            p.x = wb.x * WSCALE; p.y = wb.y * WSCALE; split2(p, wh[2], wl[2]);
            p.x = wb.z * WSCALE; p.y = wb.w * WSCALE; split2(p, wh[3], wl[3]);
        }
        f16x8 whi = cat4(wh[0], wh[1], wh[2], wh[3]);
        f16x8 wlo = cat4(wl[0], wl[1], wl[2], wl[3]);

        f32x4 rva = *(const f32x4*)(lds + REFO + ml * 132 + kc * 32 + grp * 8);
        f32x4 rvb = *(const f32x4*)(lds + REFO + ml * 132 + kc * 32 + grp * 8 + 4);
        float rv[8] = {rva.x, rva.y, rva.z, rva.w, rvb.x, rvb.y, rvb.z, rvb.w};

#define UVBODY(i) {                                                           \
        const int cb = (vA[i] * 24 + ml + uA[i]) * 36 + grp * 8;              \
        f32x4 ta = *(const f32x4*)(lds + cb);                                 \
        f32x4 tb = *(const f32x4*)(lds + cb + 4);                             \
        float t8[8] = {ta.x, ta.y, ta.z, ta.w, tb.x, tb.y, tb.z, tb.w};       \
        f16x2 xh4[4], xl4[4];                                                 \
        _Pragma("unroll")                                                     \
        for (int jp = 0; jp < 4; ++jp) {                                      \
            f32x2 p;  p.x = rv[2 * jp] * t8[2 * jp];                          \
                      p.y = rv[2 * jp + 1] * t8[2 * jp + 1];                  \
            f32x2 p1 = p * 0.1f;                                              \
            p = __builtin_elementwise_max(p, p1);                             \
            split2(p, xh4[jp], xl4[jp]);                                      \
        }                                                                     \
        f16x8 xhi = cat4(xh4[0], xh4[1], xh4[2], xh4[3]);                     \
        f16x8 xlo = cat4(xl4[0], xl4[1], xl4[2], xl4[3]);                     \
        acc[i] = __builtin_amdgcn_mfma_f32_16x16x32_f16(whi, xhi, acc[i], 0, 0, 0); \
        acc[i] = __builtin_amdgcn_mfma_f32_16x16x32_f16(wlo, xhi, acc[i], 0, 0, 0); \
        acc[i] = __builtin_amdgcn_mfma_f32_16x16x32_f16(whi, xlo, acc[i], 0, 0, 0); }

        #pragma unroll
        for (int i = 0; i < 10; ++i) UVBODY(i);
        if (wid == 0) UVBODY(10);
    }
    __syncthreads();                     // staging dead; epilogue reuses LDS

    // ---- epilogue: 4 passes of 4 f-planes; flow_reg per (f, px) ----
    const int rem = t & 63;
    const int fl  = rem >> 4;
    const int px  = rem & 15;

    for (int P = 0; P < 4; ++P) {
        // bounce this wave's uv-chunk for f = 4P..4P+3 (lanes grp==P hold them)
#define BOUNCE(i) {                                                           \
        if (grp == P) {                                                       \
            int ba = (start + (i)) * 18 + ml;                                 \
            lds[ba         ] = acc[i][0] * UNSCALE;                           \
            lds[ba + 1458  ] = acc[i][1] * UNSCALE;                           \
            lds[ba + 2916  ] = acc[i][2] * UNSCALE;                           \
            lds[ba + 4374  ] = acc[i][3] * UNSCALE; } }
        #pragma unroll
        for (int i = 0; i < 10; ++i) BOUNCE(i);
        if (wid == 0) BOUNCE(10);
        __syncthreads();

        // PH1: per-thread local argmax over its chunk (ascending, strict >)
        float vv[11];
        #pragma unroll
        for (int i = 0; i < 10; ++i)
            vv[i] = lds[fl * 1458 + (start + i) * 18 + px];
        if (wid == 0) vv[10] = lds[fl * 1458 + 10 * 18 + px];
        float mv = vv[0]; int bi = start;
        #pragma unroll
        for (int i = 1; i < 10; ++i)
            if (vv[i] > mv) { mv = vv[i]; bi = start + i; }
        if (wid == 0 && vv[10] > mv) { mv = vv[10]; bi = 10; }
        lds[SM_ + t] = mv; lds[SI_ + t] = (float)bi;
        __syncthreads();

        // ascending 8-chunk combine -> global first-occurrence argmax
        float m = lds[SM_ + rem]; int best = (int)lds[SI_ + rem];
        #pragma unroll
        for (int k = 1; k < 8; ++k) {
            float mk = lds[SM_ + k * 64 + rem];
            if (mk > m) { m = mk; best = (int)lds[SI_ + k * 64 + rem]; }
        }
        int ub = best / 9, vb = best - 9 * (best / 9);

        // PH2: masked/global softmax partials over the chunk
        float S = 0.f, A = 0.f, Sx = 0.f, Sy = 0.f, gS = 0.f, gA = 0.f;
#define PH2B(i) {                                                             \
        float d = vv[i] - m; float z = __expf(d);                             \
        gS += z; gA = fmaf(z, d, gA);                                         \
        int duc = uA[i] - ub, dvc = vA[i] - vb;                               \
        bool msk = (duc <= 3) && (duc >= -3) && (dvc <= 3) && (dvc >= -3);    \
        float zm = msk ? z : 0.f, dm = msk ? d : 0.f;                         \
        S += zm; A = fmaf(zm, dm, A);                                         \
        Sx = fmaf(zm, (float)(uA[i] - MD_), Sx);                              \
        Sy = fmaf(zm, (float)(vA[i] - MD_), Sy); }
        #pragma unroll
        for (int i = 0; i < 10; ++i) PH2B(i);
        if (wid == 0) PH2B(10);

        lds[SU_ + 0 * 512 + t] = S;  lds[SU_ + 1 * 512 + t] = A;
        lds[SU_ + 2 * 512 + t] = Sx; lds[SU_ + 3 * 512 + t] = Sy;
        lds[SU_ + 4 * 512 + t] = gS; lds[SU_ + 5 * 512 + t] = gA;
        __syncthreads();

        if (t < 64) {
            float rq[6];
            #pragma unroll
            for (int q = 0; q < 6; ++q) {
                float s = lds[SU_ + q * 512 + t];
                #pragma unroll
                for (int k = 1; k < 8; ++k) s += lds[SU_ + q * 512 + k * 64 + t];
                rq[q] = s;
            }
            float invS = 1.f / rq[0];
            float outx = rq[2] * invS;
            float outy = rq[3] * invS;
            float lent = (logf(rq[0]) - rq[1] * invS) * (1.0f / logf(49.0f));
            float gent = (logf(rq[4]) - rq[5] / rq[4]) * (1.0f / logf(81.0f));
            float* op = out0 + ((size_t)(b * F_ + P * 4 + (t >> 4)) * 4) * HW_
                      + y * W_ + x0 + (t & 15);
            op[0 * HW_] = outx;
            op[1 * HW_] = outy;
            op[2 * HW_] = lent;
            op[3 * HW_] = gent;
        }
        __syncthreads();                 // protect pvol/scratch for next pass
    }
}

__global__ __launch_bounds__(256)
void warp_kernel(const float* __restrict__ tar,
                 const float* __restrict__ out0,
                 float* __restrict__ warped) {
    int tid = blockIdx.x * 256 + threadIdx.x;   // over B_*C_*HW_
    int pix = tid & (HW_ - 1);
    int bc  = tid >> 12;
    int b   = bc >> 7;                          // C_ = 128
    int x = pix & 63, y = pix >> 6;

    // flow = hypothesis f=0 of out0 for this b
    const float* fbase = out0 + (size_t)(b * F_) * 4 * HW_;
    float fx = fbase[pix];
    float fy = fbase[HW_ + pix];
    float px = (float)x + fx;
    float py = (float)y + fy;

    bool inb = (fabsf(2.0f * px / (float)(W_ - 1) - 1.0f) < 1.0f) &&
               (fabsf(2.0f * py / (float)(H_ - 1) - 1.0f) < 1.0f);

    float x0 = floorf(px), y0 = floorf(py);
    float wx = px - x0,    wy = py - y0;
    int x0i = (int)x0, y0i = (int)y0;

    const float* img = tar + (size_t)bc * HW_;

    auto tap = [&](int yi, int xi, float wgt) -> float {
        bool v = ((unsigned)xi < (unsigned)W_) && ((unsigned)yi < (unsigned)H_);
        int xc = xi < 0 ? 0 : (xi > W_ - 1 ? W_ - 1 : xi);
        int yc = yi < 0 ? 0 : (yi > H_ - 1 ? H_ - 1 : yi);
        float val = img[yc * W_ + xc];
        return val * (v ? wgt : 0.f);
    };

    float acc = tap(y0i,     x0i,     (1.f - wx) * (1.f - wy))
              + tap(y0i,     x0i + 1, wx * (1.f - wy))
              + tap(y0i + 1, x0i,     (1.f - wx) * wy)
              + tap(y0i + 1, x0i + 1, wx * wy);

    warped[tid] = inb ? acc : 0.f;
}

extern "C" void kernel_launch(void* const* d_in, const int* in_sizes, int n_in,
                              void* d_out, int out_size, void* d_ws, size_t ws_size,
                              hipStream_t stream) {
    const float* ref = (const float*)d_in[0];
    const float* tar = (const float*)d_in[1];
    const float* pw  = (const float*)d_in[2];
    float* out0 = (float*)d_out;                       // (B*F, 4, H, W)
    float* out1 = out0 + (size_t)BF_ * 4 * HW_;        // (B, C, H, W)
    (void)d_ws; (void)ws_size;                         // workspace unused

    fused_kernel<<<512, 512, 0, stream>>>(ref, tar, pw, out0);
    warp_kernel<<<(B_ * C_ * HW_) / 256, 256, 0, stream>>>(tar, out0, out1);
}

// Round 7
// 112.625 us; speedup vs baseline: 1.1694x; 1.1694x over previous
//
#include <hip/hip_runtime.h>
#include <math.h>

#define B_ 2
#define C_ 128
#define H_ 64
#define W_ 64
#define F_ 16
#define U_ 9
#define MD_ 4
#define UV_ 81
#define HW_ (H_*W_)
#define BF_ (B_*F_)

typedef float f32x4 __attribute__((ext_vector_type(4)));
typedef float f32x2 __attribute__((ext_vector_type(2)));
typedef _Float16 f16x2 __attribute__((ext_vector_type(2)));
typedef _Float16 f16x4 __attribute__((ext_vector_type(4)));
typedef _Float16 f16x8 __attribute__((ext_vector_type(8)));

// Scales (exact powers of two; leaky_relu commutes with positive scaling).
// fp16 hi/lo split -> ~2^-21 rel error per term (verified r2/r4/r5/r6).
#define XSCALE   64.0f
#define WSCALE   256.0f
#define UNSCALE  (1.0f / 16384.0f)

// LDS map (floats), per 512-thr block (16-px tile):
//  staging:  [0, 7344)      tarT[seg*34 + c]  seg = r*24+col (r=0..8,col=0..23), c=0..31
//            [7344, 9456)   refT[px*132 + c]  px=0..15, c=0..127 (all kc, staged once)
//  epilogue: [0, 5832)      pvol[(fl*81+uv)*18 + px]
//            [5832,6344) sm ; [6344,6856) si ; [6856,9928) sred[6][512]
#define TSTR 34
#define REFO 7344
#define SM_  5832
#define SI_  6344
#define SU_  6856
#define LDSZ 9928

static __device__ __forceinline__ f16x8 cat4(f16x2 a, f16x2 b, f16x2 c, f16x2 d) {
    f16x4 ab = __builtin_shufflevector(a, b, 0, 1, 2, 3);
    f16x4 cd = __builtin_shufflevector(c, d, 0, 1, 2, 3);
    return __builtin_shufflevector(ab, cd, 0, 1, 2, 3, 4, 5, 6, 7);
}

// exact hi/lo fp16 split of a packed f32 pair
static __device__ __forceinline__ void split2(f32x2 p, f16x2& hi, f16x2& lo) {
    hi = __builtin_bit_cast(f16x2, __builtin_amdgcn_cvt_pkrtz(p.x, p.y));
    f32x2 hf; hf.x = (float)hi.x; hf.y = (float)hi.y;
    f32x2 l = p - hf;
    lo = __builtin_bit_cast(f16x2, __builtin_amdgcn_cvt_pkrtz(l.x, l.y));
}

// Fused cost-volume + flow_reg v3.
// Block = 512 thr = 8 waves = 8 uv-chunks (11,10x7 ascending), 16-px tile.
// Grid = 512 = (b, y, xq) XCD-chunked -> 2 blocks/CU (launch_bounds caps VGPR at
// 128: empirically the 2nd arg acts as min-blocks/CU on this compiler; r6's
// (512,4) forced 64 VGPR and spilled ~76 MB/dispatch to scratch).
// MFMA 16x16x32_f16: A = W[16f][32c], B = X[32c][16px]; D row f=grp*4+r, col=ml
// (fragment mapping verified by passing r2/r4/r5/r6 runs).
__global__ __launch_bounds__(512, 2)
void fused_kernel(const float* __restrict__ ref,
                  const float* __restrict__ tar,
                  const float* __restrict__ pw,
                  float* __restrict__ out0) {
    const int t    = threadIdx.x;
    const int lane = t & 63;
    const int wid  = t >> 6;            // wave = uv-chunk
    const int ml   = lane & 15;         // B col = pixel ; A row = f
    const int grp  = lane >> 4;         // k-group (c = grp*8+j) ; D: f = grp*4+r

    // XCD-chunked bijective decode: grid 512 = 8 XCD x 64 contiguous (b,y,xq)
    const int n0 = blockIdx.x;
    const int L  = (n0 & 7) * 64 + (n0 >> 3);
    const int b  = L >> 8;
    const int y  = (L >> 2) & 63;
    const int x0 = (L & 3) * 16;

    const int start = wid ? (1 + wid * 10) : 0;   // chunk [start, start+n), n = wid?10:11

    __shared__ float lds[LDSZ];

    const float* refB = ref + ((size_t)b * C_) * HW_ + y * W_ + x0;
    const float* tarB = tar + ((size_t)b * C_) * HW_;

    // uv decode for this wave's chunk (i=10 only used by wave 0)
    int uA[11], vA[11];
    #pragma unroll
    for (int i = 0; i < 11; ++i) {
        int uv = start + i;
        int uu = uv / 9;
        uA[i] = uu; vA[i] = uv - uu * 9;
    }

    // ---- stage refT once (all 128 c), scaled x64 ----
    #pragma unroll
    for (int it = 0; it < 4; ++it) {
        int idx = it * 512 + t;
        int c = idx >> 4, px = idx & 15;
        lds[REFO + px * 132 + c] = refB[(size_t)c * HW_ + px] * XSCALE;
    }

    float nstg[14];
    // tar tile per kc: 32c x 9r x 24col = 6912 elements, OOB -> 0
#define SISSUE(KC) {                                                          \
    _Pragma("unroll")                                                         \
    for (int it = 0; it < 14; ++it) {                                         \
        int idx = it * 512 + t;                                               \
        int c0  = idx / 216;                                                  \
        int rm  = idx - c0 * 216;                                             \
        int r   = rm / 24;                                                    \
        int col = rm - r * 24;                                                \
        int ysr = y + r - 4;                                                  \
        int xg  = x0 - 4 + col;                                               \
        bool ok = (idx < 6912) && ((unsigned)ysr < 64u) && ((unsigned)xg < 64u); \
        int cc  = c0 > 31 ? 31 : c0;                                          \
        int ysc = ysr < 0 ? 0 : (ysr > 63 ? 63 : ysr);                        \
        int xgc = xg  < 0 ? 0 : (xg  > 63 ? 63 : xg);                         \
        float vL = tarB[(size_t)((KC) * 32 + cc) * HW_ + ysc * W_ + xgc];     \
        nstg[it] = ok ? vL : 0.f;                                             \
    } }

#define SWRITE() {                                                            \
    _Pragma("unroll")                                                         \
    for (int it = 0; it < 14; ++it) {                                         \
        int idx = it * 512 + t;                                               \
        if (idx < 6912) {                                                     \
            int c0 = idx / 216;                                               \
            int rm = idx - c0 * 216;                                          \
            lds[rm * TSTR + c0] = nstg[it];                                   \
        }                                                                     \
    } }

    f32x4 acc[11];
    #pragma unroll
    for (int i = 0; i < 11; ++i) acc[i] = f32x4{0.f, 0.f, 0.f, 0.f};

    SISSUE(0);

    for (int kc = 0; kc < 4; ++kc) {
        f32x4 wa = *(const f32x4*)(pw + ml * C_ + kc * 32 + grp * 8);
        f32x4 wb = *(const f32x4*)(pw + ml * C_ + kc * 32 + grp * 8 + 4);

        __syncthreads();                 // previous chunk's readers done
        SWRITE();
        if (kc < 3) SISSUE(kc + 1);      // next chunk in flight during compute
        __syncthreads();                 // staged tile ready

        f16x2 wh[4], wl[4];
        {
            f32x2 p;
            p.x = wa.x * WSCALE; p.y = wa.y * WSCALE; split2(p, wh[0], wl[0]);
            p.x = wa.z * WSCALE; p.y = wa.w * WSCALE; split2(p, wh[1], wl[1]);
            p.x = wb.x * WSCALE; p.y = wb.y * WSCALE; split2(p, wh[2], wl[2]);
            p.x = wb.z * WSCALE; p.y = wb.w * WSCALE; split2(p, wh[3], wl[3]);
        }
        f16x8 whi = cat4(wh[0], wh[1], wh[2], wh[3]);
        f16x8 wlo = cat4(wl[0], wl[1], wl[2], wl[3]);

        // ref fragment: 2 x ds_read_b128, stride 132 -> 2-way (free)
        f32x4 rva = *(const f32x4*)(lds + REFO + ml * 132 + kc * 32 + grp * 8);
        f32x4 rvb = *(const f32x4*)(lds + REFO + ml * 132 + kc * 32 + grp * 8 + 4);
        f32x2 rv2[4];
        rv2[0].x = rva.x; rv2[0].y = rva.y;
        rv2[1].x = rva.z; rv2[1].y = rva.w;
        rv2[2].x = rvb.x; rv2[2].y = rvb.y;
        rv2[3].x = rvb.z; rv2[3].y = rvb.w;

        // tar fragment: 4 x ds_read_b64 (addr = even*34 + grp*8, 8B-aligned),
        // banks 2ml+8grp -> 2-way (free)
#define UVBODY(i) {                                                           \
        const int cb = (vA[i] * 24 + ml + uA[i]) * TSTR + grp * 8;            \
        f16x2 xh4[4], xl4[4];                                                 \
        _Pragma("unroll")                                                     \
        for (int jp = 0; jp < 4; ++jp) {                                      \
            f32x2 tj = *(const f32x2*)(lds + cb + 2 * jp);                    \
            f32x2 p  = rv2[jp] * tj;                                          \
            f32x2 p1 = p * 0.1f;                                              \
            p = __builtin_elementwise_max(p, p1);                             \
            split2(p, xh4[jp], xl4[jp]);                                      \
        }                                                                     \
        f16x8 xhi = cat4(xh4[0], xh4[1], xh4[2], xh4[3]);                     \
        f16x8 xlo = cat4(xl4[0], xl4[1], xl4[2], xl4[3]);                     \
        acc[i] = __builtin_amdgcn_mfma_f32_16x16x32_f16(whi, xhi, acc[i], 0, 0, 0); \
        acc[i] = __builtin_amdgcn_mfma_f32_16x16x32_f16(wlo, xhi, acc[i], 0, 0, 0); \
        acc[i] = __builtin_amdgcn_mfma_f32_16x16x32_f16(whi, xlo, acc[i], 0, 0, 0); }

        #pragma unroll
        for (int i = 0; i < 10; ++i) UVBODY(i);
        if (wid == 0) UVBODY(10);
    }
    __syncthreads();                     // staging dead; epilogue reuses LDS

    // ---- epilogue: 4 passes of 4 f-planes; flow_reg per (f, px) ----
    const int rem = t & 63;
    const int fl  = rem >> 4;
    const int px  = rem & 15;

    for (int P = 0; P < 4; ++P) {
        // bounce this wave's uv-chunk for f = 4P..4P+3 (lanes grp==P hold them)
#define BOUNCE(i) {                                                           \
        if (grp == P) {                                                       \
            int ba = (start + (i)) * 18 + ml;                                 \
            lds[ba        ] = acc[i][0] * UNSCALE;                            \
            lds[ba + 1458 ] = acc[i][1] * UNSCALE;                            \
            lds[ba + 2916 ] = acc[i][2] * UNSCALE;                            \
            lds[ba + 4374 ] = acc[i][3] * UNSCALE; } }
        #pragma unroll
        for (int i = 0; i < 10; ++i) BOUNCE(i);
        if (wid == 0) BOUNCE(10);
        __syncthreads();

        // PH1: per-thread local argmax over its chunk (ascending, strict >)
        float vv[11];
        #pragma unroll
        for (int i = 0; i < 10; ++i)
            vv[i] = lds[fl * 1458 + (start + i) * 18 + px];
        if (wid == 0) vv[10] = lds[fl * 1458 + 10 * 18 + px];
        float mv = vv[0]; int bi = start;
        #pragma unroll
        for (int i = 1; i < 10; ++i)
            if (vv[i] > mv) { mv = vv[i]; bi = start + i; }
        if (wid == 0 && vv[10] > mv) { mv = vv[10]; bi = 10; }
        lds[SM_ + t] = mv; lds[SI_ + t] = (float)bi;
        __syncthreads();

        // ascending 8-chunk combine -> global first-occurrence argmax
        float m = lds[SM_ + rem]; int best = (int)lds[SI_ + rem];
        #pragma unroll
        for (int k = 1; k < 8; ++k) {
            float mk = lds[SM_ + k * 64 + rem];
            if (mk > m) { m = mk; best = (int)lds[SI_ + k * 64 + rem]; }
        }
        int ub = best / 9, vb = best - 9 * (best / 9);

        // PH2: masked/global softmax partials over the chunk
        float S = 0.f, A = 0.f, Sx = 0.f, Sy = 0.f, gS = 0.f, gA = 0.f;
#define PH2B(i) {                                                             \
        float d = vv[i] - m; float z = __expf(d);                             \
        gS += z; gA = fmaf(z, d, gA);                                         \
        int duc = uA[i] - ub, dvc = vA[i] - vb;                               \
        bool msk = (duc <= 3) && (duc >= -3) && (dvc <= 3) && (dvc >= -3);    \
        float zm = msk ? z : 0.f, dm = msk ? d : 0.f;                         \
        S += zm; A = fmaf(zm, dm, A);                                         \
        Sx = fmaf(zm, (float)(uA[i] - MD_), Sx);                              \
        Sy = fmaf(zm, (float)(vA[i] - MD_), Sy); }
        #pragma unroll
        for (int i = 0; i < 10; ++i) PH2B(i);
        if (wid == 0) PH2B(10);

        lds[SU_ + 0 * 512 + t] = S;  lds[SU_ + 1 * 512 + t] = A;
        lds[SU_ + 2 * 512 + t] = Sx; lds[SU_ + 3 * 512 + t] = Sy;
        lds[SU_ + 4 * 512 + t] = gS; lds[SU_ + 5 * 512 + t] = gA;
        __syncthreads();

        if (t < 64) {
            float rq[6];
            #pragma unroll
            for (int q = 0; q < 6; ++q) {
                float s = lds[SU_ + q * 512 + t];
                #pragma unroll
                for (int k = 1; k < 8; ++k) s += lds[SU_ + q * 512 + k * 64 + t];
                rq[q] = s;
            }
            float invS = 1.f / rq[0];
            float outx = rq[2] * invS;
            float outy = rq[3] * invS;
            float lent = (logf(rq[0]) - rq[1] * invS) * (1.0f / logf(49.0f));
            float gent = (logf(rq[4]) - rq[5] / rq[4]) * (1.0f / logf(81.0f));
            float* op = out0 + ((size_t)(b * F_ + P * 4 + (t >> 4)) * 4) * HW_
                      + y * W_ + x0 + (t & 15);
            op[0 * HW_] = outx;
            op[1 * HW_] = outy;
            op[2 * HW_] = lent;
            op[3 * HW_] = gent;
        }
        __syncthreads();                 // protect pvol/scratch for next pass
    }
}

__global__ __launch_bounds__(256)
void warp_kernel(const float* __restrict__ tar,
                 const float* __restrict__ out0,
                 float* __restrict__ warped) {
    int tid = blockIdx.x * 256 + threadIdx.x;   // over B_*C_*HW_
    int pix = tid & (HW_ - 1);
    int bc  = tid >> 12;
    int b   = bc >> 7;                          // C_ = 128
    int x = pix & 63, y = pix >> 6;

    // flow = hypothesis f=0 of out0 for this b
    const float* fbase = out0 + (size_t)(b * F_) * 4 * HW_;
    float fx = fbase[pix];
    float fy = fbase[HW_ + pix];
    float px = (float)x + fx;
    float py = (float)y + fy;

    bool inb = (fabsf(2.0f * px / (float)(W_ - 1) - 1.0f) < 1.0f) &&
               (fabsf(2.0f * py / (float)(H_ - 1) - 1.0f) < 1.0f);

    float x0 = floorf(px), y0 = floorf(py);
    float wx = px - x0,    wy = py - y0;
    int x0i = (int)x0, y0i = (int)y0;

    const float* img = tar + (size_t)bc * HW_;

    auto tap = [&](int yi, int xi, float wgt) -> float {
        bool v = ((unsigned)xi < (unsigned)W_) && ((unsigned)yi < (unsigned)H_);
        int xc = xi < 0 ? 0 : (xi > W_ - 1 ? W_ - 1 : xi);
        int yc = yi < 0 ? 0 : (yi > H_ - 1 ? H_ - 1 : yi);
        float val = img[yc * W_ + xc];
        return val * (v ? wgt : 0.f);
    };

    float acc = tap(y0i,     x0i,     (1.f - wx) * (1.f - wy))
              + tap(y0i,     x0i + 1, wx * (1.f - wy))
              + tap(y0i + 1, x0i,     (1.f - wx) * wy)
              + tap(y0i + 1, x0i + 1, wx * wy);

    warped[tid] = inb ? acc : 0.f;
}

extern "C" void kernel_launch(void* const* d_in, const int* in_sizes, int n_in,
                              void* d_out, int out_size, void* d_ws, size_t ws_size,
                              hipStream_t stream) {
    const float* ref = (const float*)d_in[0];
    const float* tar = (const float*)d_in[1];
    const float* pw  = (const float*)d_in[2];
    float* out0 = (float*)d_out;                       // (B*F, 4, H, W)
    float* out1 = out0 + (size_t)BF_ * 4 * HW_;        // (B, C, H, W)
    (void)d_ws; (void)ws_size;                         // workspace unused

    fused_kernel<<<512, 512, 0, stream>>>(ref, tar, pw, out0);
    warp_kernel<<<(B_ * C_ * HW_) / 256, 256, 0, stream>>>(tar, out0, out1);
}

// Round 8
// 106.588 us; speedup vs baseline: 1.2356x; 1.0566x over previous
//
#include <hip/hip_runtime.h>
#include <math.h>

#define B_ 2
#define C_ 128
#define H_ 64
#define W_ 64
#define F_ 16
#define U_ 9
#define MD_ 4
#define HW_ (H_*W_)
#define BF_ (B_*F_)

typedef float f32x4 __attribute__((ext_vector_type(4)));
typedef float f32x2 __attribute__((ext_vector_type(2)));
typedef _Float16 f16x2 __attribute__((ext_vector_type(2)));
typedef _Float16 f16x4 __attribute__((ext_vector_type(4)));
typedef _Float16 f16x8 __attribute__((ext_vector_type(8)));

// Scales (exact powers of two; leaky_relu commutes with positive scaling).
// fp16 hi/lo split -> ~2^-21 rel error per term (verified r2/r4/r5/r6/r7).
#define XSCALE   64.0f
#define WSCALE   256.0f
#define UNSCALE  (1.0f / 16384.0f)

// LDS map (floats), per 512-thr block (16-px tile):
//  [0,7344)       tar buf0: [seg*34 + c], seg = r*24+col (r 0..8, col 0..23), c 0..31
//  [7344,14688)   tar buf1 (double buffer -> 1 barrier per kc)
//  [14688,16800)  refT[px*132 + c], px 0..15, c 0..127 (staged once)
//  epilogue reuse:[0,5832) pvol[(fl*81+uv)*18+px] ; [5832,6344) sm ;
//                 [6344,6856) si ; [6856,9928) sred[6][512] ; [9928,9960) fx,fy
#define TB0  0
#define TB1  7344
#define TSTR 34
#define REFO 14688
#define SM_  5832
#define SI_  6344
#define SU_  6856
#define FX_  9928
#define FY_  9944
#define LDSZ 16800

static __device__ __forceinline__ f16x8 cat4(f16x2 a, f16x2 b, f16x2 c, f16x2 d) {
    f16x4 ab = __builtin_shufflevector(a, b, 0, 1, 2, 3);
    f16x4 cd = __builtin_shufflevector(c, d, 0, 1, 2, 3);
    return __builtin_shufflevector(ab, cd, 0, 1, 2, 3, 4, 5, 6, 7);
}

// exact hi/lo fp16 split of a packed f32 pair
static __device__ __forceinline__ void split2(f32x2 p, f16x2& hi, f16x2& lo) {
    hi = __builtin_bit_cast(f16x2, __builtin_amdgcn_cvt_pkrtz(p.x, p.y));
    f32x2 hf; hf.x = (float)hi.x; hf.y = (float)hi.y;
    f32x2 l = p - hf;
    lo = __builtin_bit_cast(f16x2, __builtin_amdgcn_cvt_pkrtz(l.x, l.y));
}

// Fused cost-volume + flow_reg + warp v4.
// Block = 512 thr = 8 waves = 8 uv-chunks (11,10x7 ascending), 16-px tile.
// Grid = 512 = (b,y,xq) XCD-chunked; launch_bounds(512,2) = min 2 blocks/CU
// (empirical: 2nd arg is min-blocks/CU; (512,4) forced 64 VGPR and spilled).
// MFMA 16x16x32_f16: A = W[16f][32c], B = X[32c][16px]; D row f=grp*4+r, col=ml
// (fragment mapping verified by r2/r4/r5/r6/r7 passes).
__global__ __launch_bounds__(512, 2)
void fused_kernel(const float* __restrict__ ref,
                  const float* __restrict__ tar,
                  const float* __restrict__ pw,
                  float* __restrict__ out0,
                  float* __restrict__ warped) {
    const int t    = threadIdx.x;
    const int lane = t & 63;
    const int wid  = t >> 6;            // wave = uv-chunk
    const int ml   = lane & 15;         // B col = pixel ; A row = f
    const int grp  = lane >> 4;         // k-group (c = grp*8+j) ; D: f = grp*4+r

    // XCD-chunked bijective decode: grid 512 = 8 XCD x 64 contiguous (b,y,xq)
    const int n0 = blockIdx.x;
    const int L  = (n0 & 7) * 64 + (n0 >> 3);
    const int b  = L >> 8;
    const int y  = (L >> 2) & 63;
    const int x0 = (L & 3) * 16;

    const int start = wid ? (1 + wid * 10) : 0;   // chunk [start,start+n), n=wid?10:11

    __shared__ float lds[LDSZ];

    const float* refB = ref + ((size_t)b * C_) * HW_ + y * W_ + x0;
    const float* tarB = tar + ((size_t)b * C_) * HW_;

    // uv decode for this wave's chunk (i=10 only used by wave 0)
    int uA[11], vA[11];
    #pragma unroll
    for (int i = 0; i < 11; ++i) {
        int uv = start + i;
        int uu = uv / 9;
        uA[i] = uu; vA[i] = uv - uu * 9;
    }

    // ---- stage refT once (2048 elems), scaled x64 ----
    #pragma unroll
    for (int it = 0; it < 4; ++it) {
        int idx = it * 512 + t;
        int c = idx >> 4, px = idx & 15;
        lds[REFO + px * 132 + c] = refB[(size_t)c * HW_ + px] * XSCALE;
    }

    // ---- role-based tar staging: t<432 -> seg = t>>1 (r=seg/24, col=seg%24),
    //      16 channels each (chalf). Address math computed ONCE. ----
    const int seg   = t >> 1;
    const int chalf = (t & 1) * 16;
    const bool sactive = (seg < 216);
    const int sr   = seg / 24;             // one div, setup only
    const int scol = seg - sr * 24;
    const int ysr  = y + sr - 4;
    const int xg   = x0 - 4 + scol;
    const bool sok = sactive && ((unsigned)ysr < 64u) && ((unsigned)xg < 64u);
    const int ysc  = ysr < 0 ? 0 : (ysr > 63 ? 63 : ysr);
    const int xgc  = xg  < 0 ? 0 : (xg  > 63 ? 63 : xg);
    const float* tS = tarB + (size_t)chalf * HW_ + ysc * W_ + xgc;

    auto STAGE = [&](int kcv, int bufbase, bool zfill) {
        if (sok) {
            float* dst = lds + bufbase + seg * TSTR + chalf;
            const float* g = tS + (size_t)(kcv * 32) * HW_;
            #pragma unroll
            for (int c0 = 0; c0 < 16; ++c0) dst[c0] = g[(size_t)c0 * HW_];
        } else if (sactive && zfill) {
            float* dst = lds + bufbase + seg * TSTR + chalf;
            #pragma unroll
            for (int c0 = 0; c0 < 16; ++c0) dst[c0] = 0.f;
        }
    };

    f32x4 acc[11];
    #pragma unroll
    for (int i = 0; i < 11; ++i) acc[i] = f32x4{0.f, 0.f, 0.f, 0.f};

    STAGE(0, TB0, true);                 // prologue: kc=0 into buf0
    __syncthreads();

    #pragma unroll
    for (int kc = 0; kc < 4; ++kc) {
        const int tb = (kc & 1) ? TB1 : TB0;
        // stage kc+1 into the other buffer (its readers finished at the
        // end-of-(kc-1) barrier); zero-fill only on first use of each buffer
        if (kc == 0) STAGE(1, TB1, true);
        else if (kc == 1) STAGE(2, TB0, false);
        else if (kc == 2) STAGE(3, TB1, false);

        f32x4 wa = *(const f32x4*)(pw + ml * C_ + kc * 32 + grp * 8);
        f32x4 wb = *(const f32x4*)(pw + ml * C_ + kc * 32 + grp * 8 + 4);
        f16x2 wh[4], wl[4];
        {
            f32x2 p;
            p.x = wa.x * WSCALE; p.y = wa.y * WSCALE; split2(p, wh[0], wl[0]);
            p.x = wa.z * WSCALE; p.y = wa.w * WSCALE; split2(p, wh[1], wl[1]);
            p.x = wb.x * WSCALE; p.y = wb.y * WSCALE; split2(p, wh[2], wl[2]);
            p.x = wb.z * WSCALE; p.y = wb.w * WSCALE; split2(p, wh[3], wl[3]);
        }
        f16x8 whi = cat4(wh[0], wh[1], wh[2], wh[3]);
        f16x8 wlo = cat4(wl[0], wl[1], wl[2], wl[3]);

        // ref fragment: 2 x ds_read_b128, stride 132
        f32x4 rva = *(const f32x4*)(lds + REFO + ml * 132 + kc * 32 + grp * 8);
        f32x4 rvb = *(const f32x4*)(lds + REFO + ml * 132 + kc * 32 + grp * 8 + 4);
        f32x2 rv2[4];
        rv2[0].x = rva.x; rv2[0].y = rva.y;
        rv2[1].x = rva.z; rv2[1].y = rva.w;
        rv2[2].x = rvb.x; rv2[2].y = rvb.y;
        rv2[3].x = rvb.z; rv2[3].y = rvb.w;

#define UVBODY(i) {                                                           \
        const int cb = tb + (vA[i] * 24 + ml + uA[i]) * TSTR + grp * 8;       \
        f16x2 xh4[4], xl4[4];                                                 \
        _Pragma("unroll")                                                     \
        for (int jp = 0; jp < 4; ++jp) {                                      \
            f32x2 tj = *(const f32x2*)(lds + cb + 2 * jp);                    \
            f32x2 p  = rv2[jp] * tj;                                          \
            f32x2 p1 = p * 0.1f;                                              \
            p = __builtin_elementwise_max(p, p1);                             \
            split2(p, xh4[jp], xl4[jp]);                                      \
        }                                                                     \
        f16x8 xhi = cat4(xh4[0], xh4[1], xh4[2], xh4[3]);                     \
        f16x8 xlo = cat4(xl4[0], xl4[1], xl4[2], xl4[3]);                     \
        acc[i] = __builtin_amdgcn_mfma_f32_16x16x32_f16(whi, xhi, acc[i], 0, 0, 0); \
        acc[i] = __builtin_amdgcn_mfma_f32_16x16x32_f16(wlo, xhi, acc[i], 0, 0, 0); \
        acc[i] = __builtin_amdgcn_mfma_f32_16x16x32_f16(whi, xlo, acc[i], 0, 0, 0); }

        #pragma unroll
        for (int i = 0; i < 10; ++i) UVBODY(i);
        if (wid == 0) UVBODY(10);

        __syncthreads();                 // single barrier per kc
    }

    // ---- epilogue: 4 passes of 4 f-planes; flow_reg per (f, px) ----
    const int rem = t & 63;
    const int fl  = rem >> 4;
    const int px  = rem & 15;

    for (int P = 0; P < 4; ++P) {
        // bounce this wave's uv-chunk for f = 4P..4P+3 (lanes grp==P hold them)
#define BOUNCE(i) {                                                           \
        if (grp == P) {                                                       \
            int ba = (start + (i)) * 18 + ml;                                 \
            lds[ba        ] = acc[i][0] * UNSCALE;                            \
            lds[ba + 1458 ] = acc[i][1] * UNSCALE;                            \
            lds[ba + 2916 ] = acc[i][2] * UNSCALE;                            \
            lds[ba + 4374 ] = acc[i][3] * UNSCALE; } }
        #pragma unroll
        for (int i = 0; i < 10; ++i) BOUNCE(i);
        if (wid == 0) BOUNCE(10);
        __syncthreads();

        // PH1: per-thread local argmax over its chunk (ascending, strict >)
        float vv[11];
        #pragma unroll
        for (int i = 0; i < 10; ++i)
            vv[i] = lds[fl * 1458 + (start + i) * 18 + px];
        if (wid == 0) vv[10] = lds[fl * 1458 + 10 * 18 + px];
        float mv = vv[0]; int bi = start;
        #pragma unroll
        for (int i = 1; i < 10; ++i)
            if (vv[i] > mv) { mv = vv[i]; bi = start + i; }
        if (wid == 0 && vv[10] > mv) { mv = vv[10]; bi = 10; }
        lds[SM_ + t] = mv; lds[SI_ + t] = (float)bi;
        __syncthreads();

        // ascending 8-chunk combine -> global first-occurrence argmax
        float m = lds[SM_ + rem]; int best = (int)lds[SI_ + rem];
        #pragma unroll
        for (int k = 1; k < 8; ++k) {
            float mk = lds[SM_ + k * 64 + rem];
            if (mk > m) { m = mk; best = (int)lds[SI_ + k * 64 + rem]; }
        }
        int ub = best / 9, vb = best - 9 * (best / 9);

        // PH2: masked/global softmax partials over the chunk
        float S = 0.f, A = 0.f, Sx = 0.f, Sy = 0.f, gS = 0.f, gA = 0.f;
#define PH2B(i) {                                                             \
        float d = vv[i] - m; float z = __expf(d);                             \
        gS += z; gA = fmaf(z, d, gA);                                         \
        int duc = uA[i] - ub, dvc = vA[i] - vb;                               \
        bool msk = (duc <= 3) && (duc >= -3) && (dvc <= 3) && (dvc >= -3);    \
        float zm = msk ? z : 0.f, dm = msk ? d : 0.f;                         \
        S += zm; A = fmaf(zm, dm, A);                                         \
        Sx = fmaf(zm, (float)(uA[i] - MD_), Sx);                              \
        Sy = fmaf(zm, (float)(vA[i] - MD_), Sy); }
        #pragma unroll
        for (int i = 0; i < 10; ++i) PH2B(i);
        if (wid == 0) PH2B(10);

        lds[SU_ + 0 * 512 + t] = S;  lds[SU_ + 1 * 512 + t] = A;
        lds[SU_ + 2 * 512 + t] = Sx; lds[SU_ + 3 * 512 + t] = Sy;
        lds[SU_ + 4 * 512 + t] = gS; lds[SU_ + 5 * 512 + t] = gA;
        __syncthreads();

        if (t < 64) {
            float rq[6];
            #pragma unroll
            for (int q = 0; q < 6; ++q) {
                float s = lds[SU_ + q * 512 + t];
                #pragma unroll
                for (int k = 1; k < 8; ++k) s += lds[SU_ + q * 512 + k * 64 + t];
                rq[q] = s;
            }
            float invS = 1.f / rq[0];
            float outx = rq[2] * invS;
            float outy = rq[3] * invS;
            float lent = (logf(rq[0]) - rq[1] * invS) * (1.0f / logf(49.0f));
            float gent = (logf(rq[4]) - rq[5] / rq[4]) * (1.0f / logf(81.0f));
            float* op = out0 + ((size_t)(b * F_ + P * 4 + (t >> 4)) * 4) * HW_
                      + y * W_ + x0 + (t & 15);
            op[0 * HW_] = outx;
            op[1 * HW_] = outy;
            op[2 * HW_] = lent;
            op[3 * HW_] = gent;
            if (P == 0 && t < 16) { lds[FX_ + t] = outx; lds[FY_ + t] = outy; }
        }
        // no end-of-pass barrier needed: pass P+1's pvol/sm/su writes are all
        // ordered after its own barriers, past every pass-P reader.
    }

    // ---- fused warp tail: this block's 16 px, all 128 c (flow = f0, pass 0;
    //      FX_/FY_ written before >=2 barriers ago -> visible) ----
    {
        const int pxi = t & 15;
        const int xw  = x0 + pxi;
        float fx = lds[FX_ + pxi], fy = lds[FY_ + pxi];
        float pxw = (float)xw + fx;
        float pyw = (float)y  + fy;
        bool inb = (fabsf(2.0f * pxw / 63.0f - 1.0f) < 1.0f) &&
                   (fabsf(2.0f * pyw / 63.0f - 1.0f) < 1.0f);
        float xf = floorf(pxw), yf = floorf(pyw);
        float wx = pxw - xf, wy = pyw - yf;
        int x0i = (int)xf, y0i = (int)yf;
        auto off = [&](int yi, int xi, float wgt, float& mw) -> int {
            bool v = ((unsigned)xi < (unsigned)W_) && ((unsigned)yi < (unsigned)H_);
            int xc = xi < 0 ? 0 : (xi > W_ - 1 ? W_ - 1 : xi);
            int yc = yi < 0 ? 0 : (yi > H_ - 1 ? H_ - 1 : yi);
            mw = v ? wgt : 0.f;
            return yc * W_ + xc;
        };
        float m00, m01, m10, m11;
        int o00 = off(y0i,     x0i,     (1.f - wx) * (1.f - wy), m00);
        int o01 = off(y0i,     x0i + 1, wx * (1.f - wy),         m01);
        int o10 = off(y0i + 1, x0i,     (1.f - wx) * wy,         m10);
        int o11 = off(y0i + 1, x0i + 1, wx * wy,                 m11);
        #pragma unroll
        for (int it = 0; it < 4; ++it) {
            int c = (t >> 4) + 32 * it;
            const float* img = tarB + (size_t)c * HW_;
            float a = img[o00] * m00 + img[o01] * m01
                    + img[o10] * m10 + img[o11] * m11;
            warped[((size_t)(b * C_ + c)) * HW_ + y * W_ + xw] = inb ? a : 0.f;
        }
    }
}

extern "C" void kernel_launch(void* const* d_in, const int* in_sizes, int n_in,
                              void* d_out, int out_size, void* d_ws, size_t ws_size,
                              hipStream_t stream) {
    const float* ref = (const float*)d_in[0];
    const float* tar = (const float*)d_in[1];
    const float* pw  = (const float*)d_in[2];
    float* out0 = (float*)d_out;                       // (B*F, 4, H, W)
    float* out1 = out0 + (size_t)BF_ * 4 * HW_;        // (B, C, H, W)
    (void)d_ws; (void)ws_size;                         // workspace unused

    fused_kernel<<<512, 512, 0, stream>>>(ref, tar, pw, out0, out1);
}